// Round 22
// baseline (251.794 us; speedup 1.0000x reference)
//
#include <hip/hip_runtime.h>
#include <stdint.h>

typedef int i32x4 __attribute__((ext_vector_type(4)));

#define DEV __device__ __forceinline__

DEV void glds16(const void* g, void* l) {
  __builtin_amdgcn_global_load_lds(
      (const __attribute__((address_space(1))) void*)g,
      (__attribute__((address_space(3))) void*)l, 16, 0, 0);
}

DEV int clampi8(float f) {
  int v = (int)rintf(f);
  return v < -128 ? -128 : (v > 127 ? 127 : v);
}

// ---------------- pack int32 -> int8 (fused, 3 segments) ----------------
__global__ void pack_all_kernel(const int* __restrict__ s0, const int* __restrict__ s1,
                                const int* __restrict__ s2, int8_t* __restrict__ d0,
                                int8_t* __restrict__ d1, int8_t* __restrict__ d2) {
  const int i = blockIdx.x * 256 + threadIdx.x;  // < 5242880
  const int* s;
  int8_t* d;
  int j;
  if (i < 1048576) { s = s0; d = d0; j = i; }
  else if (i < 4194304) { s = s1; d = d1; j = i - 1048576; }
  else { s = s2; d = d2; j = i - 4194304; }
  int4 v = ((const int4*)s)[j];
  char4 c;
  c.x = (char)v.x; c.y = (char)v.y; c.z = (char)v.z; c.w = (char)v.w;
  ((char4*)d)[j] = c;
}

// ---------------- QKV: direct-to-reg GEMM, NO LDS, NO barriers ----------------
// 128x128 block, 4 waves, each wave a 64x64 sub-tile. Every MFMA fragment is
// a contiguous 16B row-chunk loaded straight from global (attn_stats pattern).
// Register double-buffer gives distance-1 prefetch; waves drift freely.
__global__ __launch_bounds__(256) void qkv_kernel(
    const int8_t* __restrict__ hs8, const int8_t* __restrict__ w8,
    const int* __restrict__ bq, int8_t* __restrict__ qb, int8_t* __restrict__ kb,
    int8_t* __restrict__ vT) {
  const int l = threadIdx.x & 63, w = threadIdx.x >> 6;
  const int wm = w >> 1, wn = w & 1;
  const int lr = l & 15, lg = l >> 4;
  const int row0 = blockIdx.y * 128, col0 = blockIdx.x * 128;
  const int8_t* pA[4];
  const int8_t* pB[4];
#pragma unroll
  for (int i = 0; i < 4; ++i)
    pA[i] = hs8 + (size_t)(row0 + (wm * 4 + i) * 16 + lr) * 2048 + lg * 16;
#pragma unroll
  for (int j = 0; j < 4; ++j)
    pB[j] = w8 + (size_t)(col0 + (wn * 4 + j) * 16 + lr) * 2048 + lg * 16;
  i32x4 acc[4][4] = {};
  i32x4 a[4], b[4], an[4], bn[4];
#pragma unroll
  for (int i = 0; i < 4; ++i) a[i] = *(const i32x4*)(pA[i]);
#pragma unroll
  for (int j = 0; j < 4; ++j) b[j] = *(const i32x4*)(pB[j]);
  for (int k0 = 0; k0 < 2048; k0 += 64) {
    if (k0 + 64 < 2048) {
#pragma unroll
      for (int i = 0; i < 4; ++i) an[i] = *(const i32x4*)(pA[i] + k0 + 64);
#pragma unroll
      for (int j = 0; j < 4; ++j) bn[j] = *(const i32x4*)(pB[j] + k0 + 64);
    }
#pragma unroll
    for (int i = 0; i < 4; ++i)
#pragma unroll
      for (int j = 0; j < 4; ++j)
        acc[i][j] = __builtin_amdgcn_mfma_i32_16x16x64_i8(a[i], b[j], acc[i][j], 0, 0, 0);
#pragma unroll
    for (int i = 0; i < 4; ++i) a[i] = an[i];
#pragma unroll
    for (int j = 0; j < 4; ++j) b[j] = bn[j];
  }
#pragma unroll
  for (int j = 0; j < 4; ++j) {
    const int col = col0 + (wn * 4 + j) * 16 + lr;
    const float bias = (float)bq[col];
    const int nh = col / 384, rem = col - nh * 384;
    const int s = rem >> 7, d = rem & 127;
#pragma unroll
    for (int i = 0; i < 4; ++i) {
#pragma unroll
      for (int r = 0; r < 4; ++r) {
        const int row = row0 + (wm * 4 + i) * 16 + lg * 4 + r;
        const int bb = row >> 10, qpos = row & 1023;
        const int n = bb * 16 + nh;
        const int8_t c = (int8_t)clampi8((float)acc[i][j][r] * 1e-4f + bias);
        if (s == 0)      qb[((size_t)n << 17) + (qpos << 7) + d] = c;
        else if (s == 1) kb[((size_t)n << 17) + (qpos << 7) + d] = c;
        else             vT[((size_t)n << 17) + (d << 10) + qpos] = c;
      }
    }
  }
}

// ---------------- attn A: per-tile softmax partial stats (no LDS, no barriers) ----
__global__ __launch_bounds__(256) void attn_stats_kernel(
    const int8_t* __restrict__ qb, const int8_t* __restrict__ kb,
    const float* __restrict__ alibi, float* __restrict__ stats) {
  const int n = blockIdx.y;
  const int tri = blockIdx.x;
  int qt = 0;
  while ((qt + 1) * (qt + 2) / 2 <= tri) ++qt;
  const int kt = tri - qt * (qt + 1) / 2;
  const int l = threadIdx.x & 63, w = threadIdx.x >> 6;
  const int lr = l & 15, lg = l >> 4;
  const int row0 = qt * 128;
  const int8_t* Qh = qb + ((size_t)n << 17);
  const int8_t* Kh = kb + ((size_t)n << 17);
  const float* al = alibi + n * 1024;

  i32x4 qa[2][2];
#pragma unroll
  for (int t = 0; t < 2; ++t)
#pragma unroll
    for (int ks = 0; ks < 2; ++ks)
      qa[t][ks] = *(const i32x4*)(Qh + (size_t)(row0 + (w * 2 + t) * 16 + lr) * 128 + ks * 64 + lg * 16);

  float sf[2][8][4];
#pragma unroll
  for (int nf = 0; nf < 8; ++nf) {
    const size_t krow = (size_t)(kt * 128 + nf * 16 + lr) * 128;
    const i32x4 bk0 = *(const i32x4*)(Kh + krow + lg * 16);
    const i32x4 bk1 = *(const i32x4*)(Kh + krow + 64 + lg * 16);
    const int col = kt * 128 + nf * 16 + lr;
    const float av = al[col];
#pragma unroll
    for (int t = 0; t < 2; ++t) {
      i32x4 sa = {0, 0, 0, 0};
      sa = __builtin_amdgcn_mfma_i32_16x16x64_i8(qa[t][0], bk0, sa, 0, 0, 0);
      sa = __builtin_amdgcn_mfma_i32_16x16x64_i8(qa[t][1], bk1, sa, 0, 0, 0);
#pragma unroll
      for (int r = 0; r < 4; ++r) {
        const int rowg = row0 + (w * 2 + t) * 16 + lg * 4 + r;
        sf[t][nf][r] = (col <= rowg)
            ? av + ((float)sa[r] * 1e-4f) * 0.08838834764831843f
            : -INFINITY;
      }
    }
  }
#pragma unroll
  for (int t = 0; t < 2; ++t)
#pragma unroll
    for (int r = 0; r < 4; ++r) {
      float tm = sf[t][0][r];
#pragma unroll
      for (int nf = 1; nf < 8; ++nf) tm = fmaxf(tm, sf[t][nf][r]);
#pragma unroll
      for (int o = 1; o < 16; o <<= 1) tm = fmaxf(tm, __shfl_xor(tm, o));
      float es = 0.f;
#pragma unroll
      for (int nf = 0; nf < 8; ++nf) es += __expf(sf[t][nf][r] - tm);
#pragma unroll
      for (int o = 1; o < 16; o <<= 1) es += __shfl_xor(es, o);
      if (lr == 0) {
        const int rowl = (w * 2 + t) * 16 + lg * 4 + r;
        float2* st = (float2*)stats;
        st[((n * 8 + qt) * 8 + kt) * 128 + rowl] = make_float2(tm, es);
      }
    }
}

// ---------------- attn B: merge stats + quantized PV (LDS-staged K/V, slabs) ----
__global__ __launch_bounds__(256) void attn_pv_kernel(
    const int8_t* __restrict__ qb, const int8_t* __restrict__ kb,
    const int8_t* __restrict__ vT, const float* __restrict__ alibi,
    const float* __restrict__ stats, int* __restrict__ slab0,
    int* __restrict__ slab1, int8_t* __restrict__ ctx) {
  __shared__ __align__(16) char lK[16384];
  __shared__ __align__(16) char lV[16384];
  __shared__ __align__(16) char lP[128 * 144];  // wave-private row bands
  const int n = blockIdx.y, gi = blockIdx.x;
  // qt = s&15, kt0 = (s>>4)&15, kt1 = (s>>8)&15; sizes 4,4,4,4,3,3,3,3,3,2,2,1
  const int sched[12] = {0x407, 0x847, 0x406, 0x403, 0x746, 0x305,
                         0x635, 0x304, 0x302, 0x534, 0x201, 0x100};
  const int s_ = sched[gi];
  const int qt = s_ & 15, kt0 = (s_ >> 4) & 15, kt1 = (s_ >> 8) & 15;
  const int l = threadIdx.x & 63, w = threadIdx.x >> 6;
  const int lr = l & 15, lg = l >> 4;
  const int row0 = qt * 128;
  const int8_t* Qh = qb + ((size_t)n << 17);
  const int8_t* Kh = kb + ((size_t)n << 17);
  const int8_t* Vh = vT + ((size_t)n << 17);
  const float* al = alibi + n * 1024;

  i32x4 qa[2][2];
#pragma unroll
  for (int t = 0; t < 2; ++t)
#pragma unroll
    for (int ks = 0; ks < 2; ++ks)
      qa[t][ks] = *(const i32x4*)(Qh + (size_t)(row0 + (w * 2 + t) * 16 + lr) * 128 + ks * 64 + lg * 16);

  // merge per-row partial stats -> global (m, s) for this q-tile
  float mrow[2][4], srow[2][4];
  const float2* st = (const float2*)stats;
#pragma unroll
  for (int t = 0; t < 2; ++t)
#pragma unroll
    for (int r = 0; r < 4; ++r) {
      const int rowl = (w * 2 + t) * 16 + lg * 4 + r;
      const int base = ((n * 8 + qt) * 8) * 128 + rowl;
      float m = -INFINITY;
      for (int k2 = 0; k2 <= qt; ++k2) m = fmaxf(m, st[base + k2 * 128].x);
      float s = 0.f;
      for (int k2 = 0; k2 <= qt; ++k2) {
        const float2 p = st[base + k2 * 128];
        s += p.y * __expf(p.x - m);
      }
      mrow[t][r] = m; srow[t][r] = s;
    }

  i32x4 pacc[2][8] = {};
  for (int kt = kt0; kt < kt1; ++kt) {
    __syncthreads();  // prior iteration's lK/lV reads complete
#pragma unroll
    for (int e0 = 0; e0 < 4; ++e0) {
      const int e = w * 4 + e0, ks = e >> 3, mb = e & 7;
      glds16(Kh + (size_t)(kt * 128 + mb * 16 + lr) * 128 + ks * 64 + lg * 16, lK + e * 1024);
      glds16(Vh + (size_t)(mb * 16 + lr) * 1024 + kt * 128 + ks * 64 + lg * 16, lV + e * 1024);
    }
    __syncthreads();  // staging visible (vmcnt drained)
    // ---- S phase: quantize P into lP (wave-private rows, no barrier after) ----
#pragma unroll
    for (int nf = 0; nf < 8; ++nf) {
      const i32x4 bk0 = *(const i32x4*)(lK + nf * 1024 + l * 16);
      const i32x4 bk1 = *(const i32x4*)(lK + (8 + nf) * 1024 + l * 16);
      const int col = kt * 128 + nf * 16 + lr;
      const float av = al[col];
#pragma unroll
      for (int t = 0; t < 2; ++t) {
        i32x4 sa = {0, 0, 0, 0};
        sa = __builtin_amdgcn_mfma_i32_16x16x64_i8(qa[t][0], bk0, sa, 0, 0, 0);
        sa = __builtin_amdgcn_mfma_i32_16x16x64_i8(qa[t][1], bk1, sa, 0, 0, 0);
#pragma unroll
        for (int r = 0; r < 4; ++r) {
          const int rowl = (w * 2 + t) * 16 + lg * 4 + r;
          const int rowg = row0 + rowl;
          int p = 0;
          if (col <= rowg) {
            const float s = av + ((float)sa[r] * 1e-4f) * 0.08838834764831843f;
            p = (int)rintf(__expf(s - mrow[t][r]) / srow[t][r] * 127.0f);
          }
          lP[rowl * 144 + nf * 16 + lr] = (char)p;
        }
      }
    }
    // ---- PV phase (lP intra-wave dep; lV read-only since stage) ----
#pragma unroll
    for (int t = 0; t < 2; ++t) {
      const int rowl = (w * 2 + t) * 16 + lr;
      const i32x4 pa0 = *(const i32x4*)(lP + rowl * 144 + lg * 16);
      const i32x4 pa1 = *(const i32x4*)(lP + rowl * 144 + 64 + lg * 16);
#pragma unroll
      for (int nf = 0; nf < 8; ++nf) {
        const i32x4 vb0 = *(const i32x4*)(lV + nf * 1024 + l * 16);
        const i32x4 vb1 = *(const i32x4*)(lV + (8 + nf) * 1024 + l * 16);
        pacc[t][nf] = __builtin_amdgcn_mfma_i32_16x16x64_i8(pa0, vb0, pacc[t][nf], 0, 0, 0);
        pacc[t][nf] = __builtin_amdgcn_mfma_i32_16x16x64_i8(pa1, vb1, pacc[t][nf], 0, 0, 0);
      }
    }
  }
  const int bb = n >> 4, nh = n & 15;
  if (qt < 4) {
#pragma unroll
    for (int t = 0; t < 2; ++t)
#pragma unroll
      for (int nf = 0; nf < 8; ++nf)
#pragma unroll
        for (int r = 0; r < 4; ++r) {
          const int qpos = row0 + (w * 2 + t) * 16 + lg * 4 + r;
          const int d = nf * 16 + lr;
          ctx[((size_t)(bb * 1024 + qpos)) * 2048 + nh * 128 + d] =
              (int8_t)clampi8((float)pacc[t][nf][r] * 2e-3f);
        }
  } else {
    int* slab = kt0 ? slab1 : slab0;
#pragma unroll
    for (int t = 0; t < 2; ++t)
#pragma unroll
      for (int nf = 0; nf < 8; ++nf)
#pragma unroll
        for (int r = 0; r < 4; ++r) {
          const int qpos = row0 + (w * 2 + t) * 16 + lg * 4 + r;
          const int d = nf * 16 + lr;
          slab[(size_t)(bb * 512 + qpos - 512) * 2048 + nh * 128 + d] = pacc[t][nf][r];
        }
  }
}

// ---------------- attn C: reduce slabs -> ctx8 for rows qpos>=512 ----------------
__global__ void ctx_reduce_kernel(const int* __restrict__ slab0,
                                  const int* __restrict__ slab1,
                                  int8_t* __restrict__ ctx) {
  const int i = blockIdx.x * blockDim.x + threadIdx.x;  // < 524288 int4s
  const int4 a = ((const int4*)slab0)[i];
  const int4 b = ((const int4*)slab1)[i];
  const int elem0 = i * 4;
  const int r512 = elem0 >> 11, col = elem0 & 2047;
  const int bb = r512 >> 9, qpos = 512 + (r512 & 511);
  char4 c;
  c.x = (char)clampi8((float)(a.x + b.x) * 2e-3f);
  c.y = (char)clampi8((float)(a.y + b.y) * 2e-3f);
  c.z = (char)clampi8((float)(a.z + b.z) * 2e-3f);
  c.w = (char)clampi8((float)(a.w + b.w) * 2e-3f);
  ((char4*)ctx)[((size_t)(bb * 1024 + qpos) * 2048 + col) >> 2] = c;
}

// ---------------- dense: 128x128 tile, 8 waves, dbuf (r18 config) ----------------
__global__ __launch_bounds__(512, 1) void dense_kernel(
    const int8_t* __restrict__ c8, const int8_t* __restrict__ w8,
    const float* __restrict__ bd, const float* __restrict__ res,
    float* __restrict__ out) {
  __shared__ __align__(16) char lA[16384];  // 2 x 8KB (128 rows x 64K)
  __shared__ __align__(16) char lB[16384];  // 2 x 8KB (128 cols x 64K)
  const int l = threadIdx.x & 63, w = threadIdx.x >> 6;
  const int wm = w >> 2, wn = w & 3;
  const int lr = l & 15, lg = l >> 4;
  const int row0 = blockIdx.y * 128, col0 = blockIdx.x * 128;
  const int8_t* pA = c8 + (size_t)(row0 + w * 16 + lr) * 2048 + lg * 16;
  const int8_t* pB = w8 + (size_t)(col0 + w * 16 + lr) * 2048 + lg * 16;
  glds16(pA, lA + w * 1024);
  glds16(pB, lB + w * 1024);
  __syncthreads();
  i32x4 acc[4][2] = {};
  int cur = 0;
  for (int k0 = 0; k0 < 2048; k0 += 64) {
    const int nxt = cur ^ 1;
    if (k0 + 64 < 2048) {
      glds16(pA + k0 + 64, lA + nxt * 8192 + w * 1024);
      glds16(pB + k0 + 64, lB + nxt * 8192 + w * 1024);
    }
    i32x4 a[4], b[2];
#pragma unroll
    for (int i = 0; i < 4; ++i)
      a[i] = *(const i32x4*)(lA + cur * 8192 + ((wm * 4 + i) * 64 + l) * 16);
#pragma unroll
    for (int j = 0; j < 2; ++j)
      b[j] = *(const i32x4*)(lB + cur * 8192 + ((wn * 2 + j) * 64 + l) * 16);
#pragma unroll
    for (int i = 0; i < 4; ++i)
#pragma unroll
      for (int j = 0; j < 2; ++j)
        acc[i][j] = __builtin_amdgcn_mfma_i32_16x16x64_i8(a[i], b[j], acc[i][j], 0, 0, 0);
    __syncthreads();
    cur = nxt;
  }
#pragma unroll
  for (int j = 0; j < 2; ++j) {
    const int col = col0 + (wn * 2 + j) * 16 + lr;
    const float bias = bd[col];
#pragma unroll
    for (int i = 0; i < 4; ++i) {
#pragma unroll
      for (int r = 0; r < 4; ++r) {
        const int row = row0 + (wm * 4 + i) * 16 + lg * 4 + r;
        const size_t o = (size_t)row * 2048 + col;
        out[o] = (float)acc[i][j][r] * 1e-5f + bias + res[o];
      }
    }
  }
}

extern "C" void kernel_launch(void* const* d_in, const int* in_sizes, int n_in,
                              void* d_out, int out_size, void* d_ws, size_t ws_size,
                              hipStream_t stream) {
  const int* hs = (const int*)d_in[0];
  const float* res = (const float*)d_in[1];
  const float* alibi = (const float*)d_in[2];
  // d_in[3] attention_mask: deterministic causal mask, computed analytically
  const int* wqkv = (const int*)d_in[4];
  const int* bqkv = (const int*)d_in[5];
  const int* wd = (const int*)d_in[6];
  const float* bd = (const float*)d_in[7];
  float* out = (float*)d_out;
  char* ws = (char*)d_ws;

  // live before/through qkv:
  int8_t* hs8   = (int8_t*)(ws + 0);          //  4 MB  [2048][2048]
  int8_t* wqkv8 = (int8_t*)(ws + 4194304);    // 12 MB  [6144][2048]
  // live after qkv (aliased over hs8/wqkv8, both dead by then):
  int*    slab0 = (int*)(ws + 0);             //  8 MB  [1024][2048] i32
  int*    slab1 = (int*)(ws + 8388608);       //  8 MB  [1024][2048] i32
  // persistent:
  int8_t* wd8   = (int8_t*)(ws + 16777216);   //  4 MB  [2048][2048]
  int8_t* q8b   = (int8_t*)(ws + 20971520);   //  4 MB  [32][1024][128]
  int8_t* k8b   = (int8_t*)(ws + 25165824);   //  4 MB  [32][1024][128]
  int8_t* vT8   = (int8_t*)(ws + 29360128);   //  4 MB  [32][128][1024]
  int8_t* ctx8  = (int8_t*)(ws + 33554432);   //  4 MB  [2048][2048]
  float*  stats = (float*)(ws + 37748736);    //  2 MB  [32][8][8][128][2] f32

  pack_all_kernel<<<20480, 256, 0, stream>>>(hs, wqkv, wd, hs8, wqkv8, wd8);
  qkv_kernel<<<dim3(48, 16), 256, 0, stream>>>(hs8, wqkv8, bqkv, q8b, k8b, vT8);
  attn_stats_kernel<<<dim3(36, 32), 256, 0, stream>>>(q8b, k8b, alibi, stats);
  attn_pv_kernel<<<dim3(12, 32), 256, 0, stream>>>(q8b, k8b, vT8, alibi, stats,
                                                   slab0, slab1, ctx8);
  ctx_reduce_kernel<<<2048, 256, 0, stream>>>(slab0, slab1, ctx8);
  dense_kernel<<<dim3(16, 16), 512, 0, stream>>>(ctx8, wd8, bd, res, out);
}

// Round 23
// 176.399 us; speedup vs baseline: 1.4274x; 1.4274x over previous
//
#include <hip/hip_runtime.h>
#include <stdint.h>

typedef int i32x4 __attribute__((ext_vector_type(4)));

#define DEV __device__ __forceinline__

DEV void glds16(const void* g, void* l) {
  __builtin_amdgcn_global_load_lds(
      (const __attribute__((address_space(1))) void*)g,
      (__attribute__((address_space(3))) void*)l, 16, 0, 0);
}

DEV int clampi8(float f) {
  int v = (int)rintf(f);
  return v < -128 ? -128 : (v > 127 ? 127 : v);
}

// ---------------- pack int32 -> int8 (fused, 3 segments) ----------------
__global__ void pack_all_kernel(const int* __restrict__ s0, const int* __restrict__ s1,
                                const int* __restrict__ s2, int8_t* __restrict__ d0,
                                int8_t* __restrict__ d1, int8_t* __restrict__ d2) {
  const int i = blockIdx.x * 256 + threadIdx.x;  // < 5242880
  const int* s;
  int8_t* d;
  int j;
  if (i < 1048576) { s = s0; d = d0; j = i; }
  else if (i < 4194304) { s = s1; d = d1; j = i - 1048576; }
  else { s = s2; d = d2; j = i - 4194304; }
  int4 v = ((const int4*)s)[j];
  char4 c;
  c.x = (char)v.x; c.y = (char)v.y; c.z = (char)v.z; c.w = (char)v.w;
  ((char4*)d)[j] = c;
}

// ---------------- QKV: 128x192 tile, 4 waves, dbuf (64 steps/CU, 2 blk/CU) ----
// Wave w: wm=w>>1 rows [wm*64,+64), wn=w&1 cols [wn*96,+96); acc[4][6],
// 24 MFMA/wave/step. Staging: A-chunks 2w,2w+1 (8); B-chunks 3w..3w+2 (12).
__global__ __launch_bounds__(256, 2) void qkv_kernel(
    const int8_t* __restrict__ hs8, const int8_t* __restrict__ w8,
    const int* __restrict__ bq, int8_t* __restrict__ qb, int8_t* __restrict__ kb,
    int8_t* __restrict__ vT) {
  __shared__ __align__(16) char lA[16384];  // 2 x 8KB  (128 rows x 64K)
  __shared__ __align__(16) char lB[24576];  // 2 x 12KB (192 cols x 64K)
  const int l = threadIdx.x & 63, w = threadIdx.x >> 6;
  const int wm = w >> 1, wn = w & 1;
  const int lr = l & 15, lg = l >> 4;
  const int row0 = blockIdx.y * 128, col0 = blockIdx.x * 192;
  const int8_t* pA0 = hs8 + (size_t)(row0 + (2 * w + 0) * 16 + lr) * 2048 + lg * 16;
  const int8_t* pA1 = hs8 + (size_t)(row0 + (2 * w + 1) * 16 + lr) * 2048 + lg * 16;
  const int8_t* pB0 = w8  + (size_t)(col0 + (3 * w + 0) * 16 + lr) * 2048 + lg * 16;
  const int8_t* pB1 = w8  + (size_t)(col0 + (3 * w + 1) * 16 + lr) * 2048 + lg * 16;
  const int8_t* pB2 = w8  + (size_t)(col0 + (3 * w + 2) * 16 + lr) * 2048 + lg * 16;
  glds16(pA0, lA + (2 * w + 0) * 1024);
  glds16(pA1, lA + (2 * w + 1) * 1024);
  glds16(pB0, lB + (3 * w + 0) * 1024);
  glds16(pB1, lB + (3 * w + 1) * 1024);
  glds16(pB2, lB + (3 * w + 2) * 1024);
  __syncthreads();
  i32x4 acc[4][6] = {};
  int cur = 0;
  for (int k0 = 0; k0 < 2048; k0 += 64) {
    const int nxt = cur ^ 1;
    if (k0 + 64 < 2048) {
      glds16(pA0 + k0 + 64, lA + nxt * 8192 + (2 * w + 0) * 1024);
      glds16(pA1 + k0 + 64, lA + nxt * 8192 + (2 * w + 1) * 1024);
      glds16(pB0 + k0 + 64, lB + nxt * 12288 + (3 * w + 0) * 1024);
      glds16(pB1 + k0 + 64, lB + nxt * 12288 + (3 * w + 1) * 1024);
      glds16(pB2 + k0 + 64, lB + nxt * 12288 + (3 * w + 2) * 1024);
    }
    i32x4 a[4], b[6];
#pragma unroll
    for (int i = 0; i < 4; ++i)
      a[i] = *(const i32x4*)(lA + cur * 8192 + ((wm * 4 + i) * 64 + l) * 16);
#pragma unroll
    for (int j = 0; j < 6; ++j)
      b[j] = *(const i32x4*)(lB + cur * 12288 + ((wn * 6 + j) * 64 + l) * 16);
#pragma unroll
    for (int i = 0; i < 4; ++i)
#pragma unroll
      for (int j = 0; j < 6; ++j)
        acc[i][j] = __builtin_amdgcn_mfma_i32_16x16x64_i8(a[i], b[j], acc[i][j], 0, 0, 0);
    __syncthreads();
    cur = nxt;
  }
#pragma unroll
  for (int j = 0; j < 6; ++j) {
    const int col = col0 + (wn * 6 + j) * 16 + lr;
    const float bias = (float)bq[col];
    const int nh = col / 384, rem = col - nh * 384;
    const int s = rem >> 7, d = rem & 127;
#pragma unroll
    for (int i = 0; i < 4; ++i) {
#pragma unroll
      for (int r = 0; r < 4; ++r) {
        const int row = row0 + (wm * 4 + i) * 16 + lg * 4 + r;
        const int bb = row >> 10, qpos = row & 1023;
        const int n = bb * 16 + nh;
        const int8_t c = (int8_t)clampi8((float)acc[i][j][r] * 1e-4f + bias);
        if (s == 0)      qb[((size_t)n << 17) + (qpos << 7) + d] = c;
        else if (s == 1) kb[((size_t)n << 17) + (qpos << 7) + d] = c;
        else             vT[((size_t)n << 17) + (d << 10) + qpos] = c;
      }
    }
  }
}

// ---------------- attn A: per-tile softmax partial stats (no LDS, no barriers) ----
__global__ __launch_bounds__(256) void attn_stats_kernel(
    const int8_t* __restrict__ qb, const int8_t* __restrict__ kb,
    const float* __restrict__ alibi, float* __restrict__ stats) {
  const int n = blockIdx.y;
  const int tri = blockIdx.x;
  int qt = 0;
  while ((qt + 1) * (qt + 2) / 2 <= tri) ++qt;
  const int kt = tri - qt * (qt + 1) / 2;
  const int l = threadIdx.x & 63, w = threadIdx.x >> 6;
  const int lr = l & 15, lg = l >> 4;
  const int row0 = qt * 128;
  const int8_t* Qh = qb + ((size_t)n << 17);
  const int8_t* Kh = kb + ((size_t)n << 17);
  const float* al = alibi + n * 1024;

  i32x4 qa[2][2];
#pragma unroll
  for (int t = 0; t < 2; ++t)
#pragma unroll
    for (int ks = 0; ks < 2; ++ks)
      qa[t][ks] = *(const i32x4*)(Qh + (size_t)(row0 + (w * 2 + t) * 16 + lr) * 128 + ks * 64 + lg * 16);

  float sf[2][8][4];
#pragma unroll
  for (int nf = 0; nf < 8; ++nf) {
    const size_t krow = (size_t)(kt * 128 + nf * 16 + lr) * 128;
    const i32x4 bk0 = *(const i32x4*)(Kh + krow + lg * 16);
    const i32x4 bk1 = *(const i32x4*)(Kh + krow + 64 + lg * 16);
    const int col = kt * 128 + nf * 16 + lr;
    const float av = al[col];
#pragma unroll
    for (int t = 0; t < 2; ++t) {
      i32x4 sa = {0, 0, 0, 0};
      sa = __builtin_amdgcn_mfma_i32_16x16x64_i8(qa[t][0], bk0, sa, 0, 0, 0);
      sa = __builtin_amdgcn_mfma_i32_16x16x64_i8(qa[t][1], bk1, sa, 0, 0, 0);
#pragma unroll
      for (int r = 0; r < 4; ++r) {
        const int rowg = row0 + (w * 2 + t) * 16 + lg * 4 + r;
        sf[t][nf][r] = (col <= rowg)
            ? av + ((float)sa[r] * 1e-4f) * 0.08838834764831843f
            : -INFINITY;
      }
    }
  }
#pragma unroll
  for (int t = 0; t < 2; ++t)
#pragma unroll
    for (int r = 0; r < 4; ++r) {
      float tm = sf[t][0][r];
#pragma unroll
      for (int nf = 1; nf < 8; ++nf) tm = fmaxf(tm, sf[t][nf][r]);
#pragma unroll
      for (int o = 1; o < 16; o <<= 1) tm = fmaxf(tm, __shfl_xor(tm, o));
      float es = 0.f;
#pragma unroll
      for (int nf = 0; nf < 8; ++nf) es += __expf(sf[t][nf][r] - tm);
#pragma unroll
      for (int o = 1; o < 16; o <<= 1) es += __shfl_xor(es, o);
      if (lr == 0) {
        const int rowl = (w * 2 + t) * 16 + lg * 4 + r;
        float2* st = (float2*)stats;
        st[((n * 8 + qt) * 8 + kt) * 128 + rowl] = make_float2(tm, es);
      }
    }
}

// ---------------- attn B: merge stats + quantized PV (LDS-staged K/V, slabs) ----
__global__ __launch_bounds__(256) void attn_pv_kernel(
    const int8_t* __restrict__ qb, const int8_t* __restrict__ kb,
    const int8_t* __restrict__ vT, const float* __restrict__ alibi,
    const float* __restrict__ stats, int* __restrict__ slab0,
    int* __restrict__ slab1, int8_t* __restrict__ ctx) {
  __shared__ __align__(16) char lK[16384];
  __shared__ __align__(16) char lV[16384];
  __shared__ __align__(16) char lP[128 * 144];  // wave-private row bands
  const int n = blockIdx.y, gi = blockIdx.x;
  // qt = s&15, kt0 = (s>>4)&15, kt1 = (s>>8)&15; sizes 4,4,4,4,3,3,3,3,3,2,2,1
  const int sched[12] = {0x407, 0x847, 0x406, 0x403, 0x746, 0x305,
                         0x635, 0x304, 0x302, 0x534, 0x201, 0x100};
  const int s_ = sched[gi];
  const int qt = s_ & 15, kt0 = (s_ >> 4) & 15, kt1 = (s_ >> 8) & 15;
  const int l = threadIdx.x & 63, w = threadIdx.x >> 6;
  const int lr = l & 15, lg = l >> 4;
  const int row0 = qt * 128;
  const int8_t* Qh = qb + ((size_t)n << 17);
  const int8_t* Kh = kb + ((size_t)n << 17);
  const int8_t* Vh = vT + ((size_t)n << 17);
  const float* al = alibi + n * 1024;

  i32x4 qa[2][2];
#pragma unroll
  for (int t = 0; t < 2; ++t)
#pragma unroll
    for (int ks = 0; ks < 2; ++ks)
      qa[t][ks] = *(const i32x4*)(Qh + (size_t)(row0 + (w * 2 + t) * 16 + lr) * 128 + ks * 64 + lg * 16);

  // merge per-row partial stats -> global (m, s) for this q-tile
  float mrow[2][4], srow[2][4];
  const float2* st = (const float2*)stats;
#pragma unroll
  for (int t = 0; t < 2; ++t)
#pragma unroll
    for (int r = 0; r < 4; ++r) {
      const int rowl = (w * 2 + t) * 16 + lg * 4 + r;
      const int base = ((n * 8 + qt) * 8) * 128 + rowl;
      float m = -INFINITY;
      for (int k2 = 0; k2 <= qt; ++k2) m = fmaxf(m, st[base + k2 * 128].x);
      float s = 0.f;
      for (int k2 = 0; k2 <= qt; ++k2) {
        const float2 p = st[base + k2 * 128];
        s += p.y * __expf(p.x - m);
      }
      mrow[t][r] = m; srow[t][r] = s;
    }

  i32x4 pacc[2][8] = {};
  for (int kt = kt0; kt < kt1; ++kt) {
    __syncthreads();  // prior iteration's lK/lV reads complete
#pragma unroll
    for (int e0 = 0; e0 < 4; ++e0) {
      const int e = w * 4 + e0, ks = e >> 3, mb = e & 7;
      glds16(Kh + (size_t)(kt * 128 + mb * 16 + lr) * 128 + ks * 64 + lg * 16, lK + e * 1024);
      glds16(Vh + (size_t)(mb * 16 + lr) * 1024 + kt * 128 + ks * 64 + lg * 16, lV + e * 1024);
    }
    __syncthreads();  // staging visible (vmcnt drained)
    // ---- S phase: quantize P into lP (wave-private rows, no barrier after) ----
#pragma unroll
    for (int nf = 0; nf < 8; ++nf) {
      const i32x4 bk0 = *(const i32x4*)(lK + nf * 1024 + l * 16);
      const i32x4 bk1 = *(const i32x4*)(lK + (8 + nf) * 1024 + l * 16);
      const int col = kt * 128 + nf * 16 + lr;
      const float av = al[col];
#pragma unroll
      for (int t = 0; t < 2; ++t) {
        i32x4 sa = {0, 0, 0, 0};
        sa = __builtin_amdgcn_mfma_i32_16x16x64_i8(qa[t][0], bk0, sa, 0, 0, 0);
        sa = __builtin_amdgcn_mfma_i32_16x16x64_i8(qa[t][1], bk1, sa, 0, 0, 0);
#pragma unroll
        for (int r = 0; r < 4; ++r) {
          const int rowl = (w * 2 + t) * 16 + lg * 4 + r;
          const int rowg = row0 + rowl;
          int p = 0;
          if (col <= rowg) {
            const float s = av + ((float)sa[r] * 1e-4f) * 0.08838834764831843f;
            p = (int)rintf(__expf(s - mrow[t][r]) / srow[t][r] * 127.0f);
          }
          lP[rowl * 144 + nf * 16 + lr] = (char)p;
        }
      }
    }
    // ---- PV phase (lP intra-wave dep; lV read-only since stage) ----
#pragma unroll
    for (int t = 0; t < 2; ++t) {
      const int rowl = (w * 2 + t) * 16 + lr;
      const i32x4 pa0 = *(const i32x4*)(lP + rowl * 144 + lg * 16);
      const i32x4 pa1 = *(const i32x4*)(lP + rowl * 144 + 64 + lg * 16);
#pragma unroll
      for (int nf = 0; nf < 8; ++nf) {
        const i32x4 vb0 = *(const i32x4*)(lV + nf * 1024 + l * 16);
        const i32x4 vb1 = *(const i32x4*)(lV + (8 + nf) * 1024 + l * 16);
        pacc[t][nf] = __builtin_amdgcn_mfma_i32_16x16x64_i8(pa0, vb0, pacc[t][nf], 0, 0, 0);
        pacc[t][nf] = __builtin_amdgcn_mfma_i32_16x16x64_i8(pa1, vb1, pacc[t][nf], 0, 0, 0);
      }
    }
  }
  const int bb = n >> 4, nh = n & 15;
  if (qt < 4) {
#pragma unroll
    for (int t = 0; t < 2; ++t)
#pragma unroll
      for (int nf = 0; nf < 8; ++nf)
#pragma unroll
        for (int r = 0; r < 4; ++r) {
          const int qpos = row0 + (w * 2 + t) * 16 + lg * 4 + r;
          const int d = nf * 16 + lr;
          ctx[((size_t)(bb * 1024 + qpos)) * 2048 + nh * 128 + d] =
              (int8_t)clampi8((float)pacc[t][nf][r] * 2e-3f);
        }
  } else {
    int* slab = kt0 ? slab1 : slab0;
#pragma unroll
    for (int t = 0; t < 2; ++t)
#pragma unroll
      for (int nf = 0; nf < 8; ++nf)
#pragma unroll
        for (int r = 0; r < 4; ++r) {
          const int qpos = row0 + (w * 2 + t) * 16 + lg * 4 + r;
          const int d = nf * 16 + lr;
          slab[(size_t)(bb * 512 + qpos - 512) * 2048 + nh * 128 + d] = pacc[t][nf][r];
        }
  }
}

// ---------------- attn C: reduce slabs -> ctx8 for rows qpos>=512 ----------------
__global__ void ctx_reduce_kernel(const int* __restrict__ slab0,
                                  const int* __restrict__ slab1,
                                  int8_t* __restrict__ ctx) {
  const int i = blockIdx.x * blockDim.x + threadIdx.x;  // < 524288 int4s
  const int4 a = ((const int4*)slab0)[i];
  const int4 b = ((const int4*)slab1)[i];
  const int elem0 = i * 4;
  const int r512 = elem0 >> 11, col = elem0 & 2047;
  const int bb = r512 >> 9, qpos = 512 + (r512 & 511);
  char4 c;
  c.x = (char)clampi8((float)(a.x + b.x) * 2e-3f);
  c.y = (char)clampi8((float)(a.y + b.y) * 2e-3f);
  c.z = (char)clampi8((float)(a.z + b.z) * 2e-3f);
  c.w = (char)clampi8((float)(a.w + b.w) * 2e-3f);
  ((char4*)ctx)[((size_t)(bb * 1024 + qpos) * 2048 + col) >> 2] = c;
}

// ---------------- dense: 128x128 tile, 8 waves, dbuf (r18 config) ----------------
__global__ __launch_bounds__(512, 1) void dense_kernel(
    const int8_t* __restrict__ c8, const int8_t* __restrict__ w8,
    const float* __restrict__ bd, const float* __restrict__ res,
    float* __restrict__ out) {
  __shared__ __align__(16) char lA[16384];  // 2 x 8KB (128 rows x 64K)
  __shared__ __align__(16) char lB[16384];  // 2 x 8KB (128 cols x 64K)
  const int l = threadIdx.x & 63, w = threadIdx.x >> 6;
  const int wm = w >> 2, wn = w & 3;
  const int lr = l & 15, lg = l >> 4;
  const int row0 = blockIdx.y * 128, col0 = blockIdx.x * 128;
  const int8_t* pA = c8 + (size_t)(row0 + w * 16 + lr) * 2048 + lg * 16;
  const int8_t* pB = w8 + (size_t)(col0 + w * 16 + lr) * 2048 + lg * 16;
  glds16(pA, lA + w * 1024);
  glds16(pB, lB + w * 1024);
  __syncthreads();
  i32x4 acc[4][2] = {};
  int cur = 0;
  for (int k0 = 0; k0 < 2048; k0 += 64) {
    const int nxt = cur ^ 1;
    if (k0 + 64 < 2048) {
      glds16(pA + k0 + 64, lA + nxt * 8192 + w * 1024);
      glds16(pB + k0 + 64, lB + nxt * 8192 + w * 1024);
    }
    i32x4 a[4], b[2];
#pragma unroll
    for (int i = 0; i < 4; ++i)
      a[i] = *(const i32x4*)(lA + cur * 8192 + ((wm * 4 + i) * 64 + l) * 16);
#pragma unroll
    for (int j = 0; j < 2; ++j)
      b[j] = *(const i32x4*)(lB + cur * 8192 + ((wn * 2 + j) * 64 + l) * 16);
#pragma unroll
    for (int i = 0; i < 4; ++i)
#pragma unroll
      for (int j = 0; j < 2; ++j)
        acc[i][j] = __builtin_amdgcn_mfma_i32_16x16x64_i8(a[i], b[j], acc[i][j], 0, 0, 0);
    __syncthreads();
    cur = nxt;
  }
#pragma unroll
  for (int j = 0; j < 2; ++j) {
    const int col = col0 + (wn * 2 + j) * 16 + lr;
    const float bias = bd[col];
#pragma unroll
    for (int i = 0; i < 4; ++i) {
#pragma unroll
      for (int r = 0; r < 4; ++r) {
        const int row = row0 + (wm * 4 + i) * 16 + lg * 4 + r;
        const size_t o = (size_t)row * 2048 + col;
        out[o] = (float)acc[i][j][r] * 1e-5f + bias + res[o];
      }
    }
  }
}

extern "C" void kernel_launch(void* const* d_in, const int* in_sizes, int n_in,
                              void* d_out, int out_size, void* d_ws, size_t ws_size,
                              hipStream_t stream) {
  const int* hs = (const int*)d_in[0];
  const float* res = (const float*)d_in[1];
  const float* alibi = (const float*)d_in[2];
  // d_in[3] attention_mask: deterministic causal mask, computed analytically
  const int* wqkv = (const int*)d_in[4];
  const int* bqkv = (const int*)d_in[5];
  const int* wd = (const int*)d_in[6];
  const float* bd = (const float*)d_in[7];
  float* out = (float*)d_out;
  char* ws = (char*)d_ws;

  // live before/through qkv:
  int8_t* hs8   = (int8_t*)(ws + 0);          //  4 MB  [2048][2048]
  int8_t* wqkv8 = (int8_t*)(ws + 4194304);    // 12 MB  [6144][2048]
  // live after qkv (aliased over hs8/wqkv8, both dead by then):
  int*    slab0 = (int*)(ws + 0);             //  8 MB  [1024][2048] i32
  int*    slab1 = (int*)(ws + 8388608);       //  8 MB  [1024][2048] i32
  // persistent:
  int8_t* wd8   = (int8_t*)(ws + 16777216);   //  4 MB  [2048][2048]
  int8_t* q8b   = (int8_t*)(ws + 20971520);   //  4 MB  [32][1024][128]
  int8_t* k8b   = (int8_t*)(ws + 25165824);   //  4 MB  [32][1024][128]
  int8_t* vT8   = (int8_t*)(ws + 29360128);   //  4 MB  [32][128][1024]
  int8_t* ctx8  = (int8_t*)(ws + 33554432);   //  4 MB  [2048][2048]
  float*  stats = (float*)(ws + 37748736);    //  2 MB  [32][8][8][128][2] f32

  pack_all_kernel<<<20480, 256, 0, stream>>>(hs, wqkv, wd, hs8, wqkv8, wd8);
  qkv_kernel<<<dim3(32, 16), 256, 0, stream>>>(hs8, wqkv8, bqkv, q8b, k8b, vT8);
  attn_stats_kernel<<<dim3(36, 32), 256, 0, stream>>>(q8b, k8b, alibi, stats);
  attn_pv_kernel<<<dim3(12, 32), 256, 0, stream>>>(q8b, k8b, vT8, alibi, stats,
                                                   slab0, slab1, ctx8);
  ctx_reduce_kernel<<<2048, 256, 0, stream>>>(slab0, slab1, ctx8);
  dense_kernel<<<dim3(16, 16), 512, 0, stream>>>(ctx8, wd8, bd, res, out);
}